// Round 2
// baseline (127.834 us; speedup 1.0000x reference)
//
#include <hip/hip_runtime.h>
#include <cstdint>
#include <cstring>
#include <algorithm>

#define NCELLS (48*48*48)   // 110592
#define NT 48
#define CB 128              // cells per block in k_cell

struct TriTab {
  int   delta[NT][3];   // element delta into offset array per (tri, vertex)
  float bx[NT][3];      // base vertex coords (incl +0.5 on axis)
  float by[NT][3];
  float bz[NT][3];
  int   axes[NT];       // a0 | a1<<2 | a2<<4
  int   tto[NT];        // TT_IDX[t]
};

// ---------------- host-side exact numpy RNG reproduction ----------------
namespace nprng {
typedef unsigned __int128 u128;
struct PCG { u128 state, inc; int has32; uint32_t cached; };

static inline u128 mult128() {
  return (((u128)2549297995355413924ULL) << 64) | (u128)4865540595714422341ULL;
}
static inline void step(PCG& g) { g.state = g.state * mult128() + g.inc; }
static inline uint64_t out64(const PCG& g) {
  uint64_t x = (uint64_t)(g.state >> 64) ^ (uint64_t)g.state;
  unsigned rot = (unsigned)(g.state >> 122);
  return (x >> rot) | (x << ((64u - rot) & 63u));
}
static inline uint64_t next64(PCG& g) { step(g); return out64(g); }
static inline uint32_t next32(PCG& g) {
  if (g.has32) { g.has32 = 0; return g.cached; }
  uint64_t v = next64(g);
  g.has32 = 1; g.cached = (uint32_t)(v >> 32);
  return (uint32_t)v;
}
static inline uint32_t lemire32(PCG& g, uint32_t rngmax) {
  const uint32_t rng_excl = rngmax + 1u;
  uint64_t m = (uint64_t)next32(g) * (uint64_t)rng_excl;
  uint32_t leftover = (uint32_t)m;
  if (leftover < rng_excl) {
    const uint32_t threshold = (uint32_t)((0xFFFFFFFFu - rngmax) % rng_excl);
    while (leftover < threshold) {
      m = (uint64_t)next32(g) * (uint64_t)rng_excl;
      leftover = (uint32_t)m;
    }
  }
  return (uint32_t)(m >> 32);
}
static inline uint64_t rbu(PCG& g, uint64_t rngmax) {
  if (rngmax == 0) return 0;
  return (uint64_t)lemire32(g, (uint32_t)rngmax);
}
static void seed_pcg0(PCG& g) {
  const uint32_t INIT_A = 0x43b0d7e5u, MULT_A = 0x931e8875u;
  const uint32_t INIT_B = 0x8b51f9ddu, MULT_B = 0x58f38dedu;
  const uint32_t MIX_L = 0xca01f9ddu, MIX_R = 0x4973f715u;
  uint32_t pool[4];
  uint32_t hc = INIT_A;
  auto hashmix = [&](uint32_t v) { v ^= hc; hc *= MULT_A; v *= hc; v ^= v >> 16; return v; };
  auto mix = [&](uint32_t x, uint32_t y) { uint32_t r = MIX_L * x - MIX_R * y; r ^= r >> 16; return r; };
  for (int i = 0; i < 4; i++) pool[i] = hashmix(0u);
  for (int s = 0; s < 4; s++)
    for (int d = 0; d < 4; d++)
      if (s != d) pool[d] = mix(pool[d], hashmix(pool[s]));
  uint32_t st[8];
  uint32_t hb = INIT_B;
  for (int i = 0; i < 8; i++) {
    uint32_t v = pool[i & 3];
    v ^= hb; hb *= MULT_B; v *= hb; v ^= v >> 16;
    st[i] = v;
  }
  uint64_t w[4];
  for (int i = 0; i < 4; i++) w[i] = (uint64_t)st[2 * i] | ((uint64_t)st[2 * i + 1] << 32);
  u128 initstate = (((u128)w[0]) << 64) | (u128)w[1];
  u128 initseq   = (((u128)w[2]) << 64) | (u128)w[3];
  g.state = 0; g.inc = (initseq << 1) | (u128)1;
  step(g); g.state += initstate; step(g);
  g.has32 = 0; g.cached = 0;
}
static void choice_nr(PCG& g, int pop, int n, int* outv, bool shuf) {
  uint64_t hs[64];
  uint64_t set_size = (uint64_t)(1.2 * (double)n);
  uint64_t mask = set_size;
  mask |= mask >> 1; mask |= mask >> 2; mask |= mask >> 4;
  mask |= mask >> 8; mask |= mask >> 16; mask |= mask >> 32;
  uint64_t ss = mask + 1;
  for (uint64_t i = 0; i < ss; i++) hs[i] = ~0ULL;
  for (int j = pop - n; j < pop; j++) {
    uint64_t val = rbu(g, (uint64_t)j);
    uint64_t loc = val & mask;
    while (hs[loc] != ~0ULL && hs[loc] != val) loc = (loc + 1) & mask;
    if (hs[loc] == ~0ULL) { hs[loc] = val; outv[j - (pop - n)] = (int)val; }
    else {
      loc = (uint64_t)j & mask;
      while (hs[loc] != ~0ULL) loc = (loc + 1) & mask;
      hs[loc] = (uint64_t)j;
      outv[j - (pop - n)] = j;
    }
  }
  if (shuf) {
    for (int i = n - 1; i >= 1; i--) {
      uint64_t j = rbu(g, (uint64_t)i);
      int t = outv[i]; outv[i] = outv[(int)j]; outv[(int)j] = t;
    }
  }
}
} // namespace nprng

static void build_tab(TriTab* T) {
  nprng::PCG g;
  nprng::seed_pcg0(g);
  int tri[NT][3];
  for (int t = 0; t < NT; t++) nprng::choice_nr(g, 12, 3, tri[t], true);
  int tt[NT];
  nprng::choice_nr(g, 96, NT, tt, true);
  std::sort(tt, tt + NT);
  static const int EC[12][3] = {{0,0,0},{0,1,0},{0,0,1},{0,1,1},
                                {0,0,0},{1,0,0},{0,0,1},{1,0,1},
                                {0,0,0},{1,0,0},{0,1,0},{1,1,0}};
  static const int EA[12] = {0,0,0,0,1,1,1,1,2,2,2,2};
  for (int t = 0; t < NT; t++) {
    int axes = 0;
    for (int k = 0; k < 3; k++) {
      int e = tri[t][k];
      int a = EA[e];
      T->delta[t][k] = a * 117649 + EC[e][0] * 2401 + EC[e][1] * 49 + EC[e][2];
      float b[3] = {(float)EC[e][0], (float)EC[e][1], (float)EC[e][2]};
      b[a] += 0.5f;
      T->bx[t][k] = b[0]; T->by[t][k] = b[1]; T->bz[t][k] = b[2];
      axes |= a << (2 * k);
    }
    T->axes[t] = axes;
    T->tto[t] = tt[t];
  }
}

// ---------------- kernels ----------------
// k_cell: CB cells/block. Topo slab for a block is LINEAR (CB*96 floats) ->
// stage via perfectly coalesced float4 loads into LDS with pitch 97
// (97 mod 32 == 1 -> conflict-free per-cell reads in compute phase).
__global__ __launch_bounds__(CB) void k_cell(const float* __restrict__ off,
                                             const float* __restrict__ topo,
                                             float4* __restrict__ ws4,
                                             float* __restrict__ out,
                                             TriTab tab) {
  __shared__ float lds[CB * 97];
  const int tid = threadIdx.x;
  const int cell0 = blockIdx.x * CB;

  // zero the output accumulator (stream-ordered before k_pair's atomics)
  if (blockIdx.x == 0 && tid == 0) *out = 0.0f;

  // ---- coalesced staging: CB rows x 24 float4 chunks, linear in global ----
  const float4* trow = (const float4*)(topo + (size_t)cell0 * 96);
#pragma unroll
  for (int it = 0; it < 24; ++it) {
    int ch = tid + CB * it;          // 0 .. CB*24-1, linear global index
    float4 v = trow[ch];
    int r  = ch / 24;
    int c4 = (ch % 24) * 4;
    float* dst = &lds[r * 97 + c4];
    dst[0] = v.x; dst[1] = v.y; dst[2] = v.z; dst[3] = v.w;
  }
  __syncthreads();

  // ---- per-cell compute ----
  const int cell = cell0 + tid;
  const int z = cell % 48;
  const int y = (cell / 48) % 48;
  const int x = cell / 2304;
  const int base = (x * 49 + y) * 49 + z;
  const float* myrow = &lds[tid * 97];

  float s = 0.f, mx = 0.f, my = 0.f, mz = 0.f;
#pragma unroll
  for (int t = 0; t < NT; t++) {
    float p = myrow[tab.tto[t]];
    float d0 = off[base + tab.delta[t][0]];
    float d1 = off[base + tab.delta[t][1]];
    float d2 = off[base + tab.delta[t][2]];
    int axes = tab.axes[t];
    int a0 = axes & 3, a1 = (axes >> 2) & 3, a2 = (axes >> 4) & 3;
    float v0x = tab.bx[t][0] + (a0 == 0 ? d0 : 0.0f);
    float v0y = tab.by[t][0] + (a0 == 1 ? d0 : 0.0f);
    float v0z = tab.bz[t][0] + (a0 == 2 ? d0 : 0.0f);
    float v1x = tab.bx[t][1] + (a1 == 0 ? d1 : 0.0f);
    float v1y = tab.by[t][1] + (a1 == 1 ? d1 : 0.0f);
    float v1z = tab.bz[t][1] + (a1 == 2 ? d1 : 0.0f);
    float v2x = tab.bx[t][2] + (a2 == 0 ? d2 : 0.0f);
    float v2y = tab.by[t][2] + (a2 == 1 ? d2 : 0.0f);
    float v2z = tab.bz[t][2] + (a2 == 2 ? d2 : 0.0f);
    float ux = v1x - v0x, uy = v1y - v0y, uz = v1z - v0z;
    float wx = v2x - v0x, wy = v2y - v0y, wz = v2z - v0z;
    float cxv = uy * wz - uz * wy;
    float cyv = uz * wx - ux * wz;
    float czv = ux * wy - uy * wx;
    float nn = cxv * cxv + cyv * cyv + czv * czv + 1e-8f;
    float rinv = rsqrtf(nn);
    s += p;
    float f = p * rinv;
    mx += f * cxv;
    my += f * cyv;
    mz += f * czv;
  }
  ws4[cell] = make_float4(s, mx, my, mz);
}

__global__ __launch_bounds__(256) void k_pair(const float4* __restrict__ ws4,
                                              float* __restrict__ out) {
  int cell = blockIdx.x * 256 + threadIdx.x;
  int z = cell % 48;
  int y = (cell / 48) % 48;
  int x = cell / 2304;
  float4 a = ws4[cell];
  float acc = a.x * a.x - (a.y * a.y + a.z * a.z + a.w * a.w);
  if (z < 47) {
    float4 b = ws4[cell + 1];
    acc += a.x * b.x - (a.y * b.y + a.z * b.z + a.w * b.w);
  }
  if (y < 47) {
    float4 b = ws4[cell + 48];
    acc += a.x * b.x - (a.y * b.y + a.z * b.z + a.w * b.w);
  }
  if (x < 47) {
    float4 b = ws4[cell + 2304];
    acc += a.x * b.x - (a.y * b.y + a.z * b.z + a.w * b.w);
  }
  acc *= 2.0f;
  // wave64 reduce
  for (int o = 32; o > 0; o >>= 1) acc += __shfl_down(acc, o, 64);
  __shared__ float lds[4];
  int lane = threadIdx.x & 63;
  int w = threadIdx.x >> 6;
  if (lane == 0) lds[w] = acc;
  __syncthreads();
  if (threadIdx.x == 0) atomicAdd(out, lds[0] + lds[1] + lds[2] + lds[3]);
}

extern "C" void kernel_launch(void* const* d_in, const int* in_sizes, int n_in,
                              void* d_out, int out_size, void* d_ws, size_t ws_size,
                              hipStream_t stream) {
  const float* off  = (const float*)d_in[0];   // [3,49,49,49] f32
  const float* topo = (const float*)d_in[1];   // [110592,96] f32
  float4* ws4 = (float4*)d_ws;                 // 110592 float4 = 1.77 MB
  float* out  = (float*)d_out;                 // scalar f32

  TriTab T;
  build_tab(&T);

  k_cell<<<dim3(NCELLS / CB), dim3(CB), 0, stream>>>(off, topo, ws4, out, T);
  k_pair<<<dim3(NCELLS / 256), dim3(256), 0, stream>>>(ws4, out);
}

// Round 3
// 99.507 us; speedup vs baseline: 1.2847x; 1.2847x over previous
//
#include <hip/hip_runtime.h>
#include <cstdint>
#include <cstring>
#include <algorithm>

#define NCELLS (48*48*48)   // 110592
#define NT 48
#define CB 64               // cells per block in k_cell
#define NW 4                // waves per block; each wave does NT/NW = 12 tris
#define TPW 12              // tris per wave
#define PITCH 97            // LDS row pitch (97 % 32 == 1 -> 2-way conflict = free)

struct TriTab {
  int   delta[NT][3];   // element delta into offset array per (tri, vertex)
  float bx[NT][3];      // base vertex coords (incl +0.5 on axis)
  float by[NT][3];
  float bz[NT][3];
  int   axes[NT];       // a0 | a1<<2 | a2<<4
  int   tto[NT];        // TT_IDX[t]
};

// ---------------- host-side exact numpy RNG reproduction ----------------
namespace nprng {
typedef unsigned __int128 u128;
struct PCG { u128 state, inc; int has32; uint32_t cached; };

static inline u128 mult128() {
  return (((u128)2549297995355413924ULL) << 64) | (u128)4865540595714422341ULL;
}
static inline void step(PCG& g) { g.state = g.state * mult128() + g.inc; }
static inline uint64_t out64(const PCG& g) {
  uint64_t x = (uint64_t)(g.state >> 64) ^ (uint64_t)g.state;
  unsigned rot = (unsigned)(g.state >> 122);
  return (x >> rot) | (x << ((64u - rot) & 63u));
}
static inline uint64_t next64(PCG& g) { step(g); return out64(g); }
static inline uint32_t next32(PCG& g) {
  if (g.has32) { g.has32 = 0; return g.cached; }
  uint64_t v = next64(g);
  g.has32 = 1; g.cached = (uint32_t)(v >> 32);
  return (uint32_t)v;
}
static inline uint32_t lemire32(PCG& g, uint32_t rngmax) {
  const uint32_t rng_excl = rngmax + 1u;
  uint64_t m = (uint64_t)next32(g) * (uint64_t)rng_excl;
  uint32_t leftover = (uint32_t)m;
  if (leftover < rng_excl) {
    const uint32_t threshold = (uint32_t)((0xFFFFFFFFu - rngmax) % rng_excl);
    while (leftover < threshold) {
      m = (uint64_t)next32(g) * (uint64_t)rng_excl;
      leftover = (uint32_t)m;
    }
  }
  return (uint32_t)(m >> 32);
}
static inline uint64_t rbu(PCG& g, uint64_t rngmax) {
  if (rngmax == 0) return 0;
  return (uint64_t)lemire32(g, (uint32_t)rngmax);
}
static void seed_pcg0(PCG& g) {
  const uint32_t INIT_A = 0x43b0d7e5u, MULT_A = 0x931e8875u;
  const uint32_t INIT_B = 0x8b51f9ddu, MULT_B = 0x58f38dedu;
  const uint32_t MIX_L = 0xca01f9ddu, MIX_R = 0x4973f715u;
  uint32_t pool[4];
  uint32_t hc = INIT_A;
  auto hashmix = [&](uint32_t v) { v ^= hc; hc *= MULT_A; v *= hc; v ^= v >> 16; return v; };
  auto mix = [&](uint32_t x, uint32_t y) { uint32_t r = MIX_L * x - MIX_R * y; r ^= r >> 16; return r; };
  for (int i = 0; i < 4; i++) pool[i] = hashmix(0u);
  for (int s = 0; s < 4; s++)
    for (int d = 0; d < 4; d++)
      if (s != d) pool[d] = mix(pool[d], hashmix(pool[s]));
  uint32_t st[8];
  uint32_t hb = INIT_B;
  for (int i = 0; i < 8; i++) {
    uint32_t v = pool[i & 3];
    v ^= hb; hb *= MULT_B; v *= hb; v ^= v >> 16;
    st[i] = v;
  }
  uint64_t w[4];
  for (int i = 0; i < 4; i++) w[i] = (uint64_t)st[2 * i] | ((uint64_t)st[2 * i + 1] << 32);
  u128 initstate = (((u128)w[0]) << 64) | (u128)w[1];
  u128 initseq   = (((u128)w[2]) << 64) | (u128)w[3];
  g.state = 0; g.inc = (initseq << 1) | (u128)1;
  step(g); g.state += initstate; step(g);
  g.has32 = 0; g.cached = 0;
}
static void choice_nr(PCG& g, int pop, int n, int* outv, bool shuf) {
  uint64_t hs[64];
  uint64_t set_size = (uint64_t)(1.2 * (double)n);
  uint64_t mask = set_size;
  mask |= mask >> 1; mask |= mask >> 2; mask |= mask >> 4;
  mask |= mask >> 8; mask |= mask >> 16; mask |= mask >> 32;
  uint64_t ss = mask + 1;
  for (uint64_t i = 0; i < ss; i++) hs[i] = ~0ULL;
  for (int j = pop - n; j < pop; j++) {
    uint64_t val = rbu(g, (uint64_t)j);
    uint64_t loc = val & mask;
    while (hs[loc] != ~0ULL && hs[loc] != val) loc = (loc + 1) & mask;
    if (hs[loc] == ~0ULL) { hs[loc] = val; outv[j - (pop - n)] = (int)val; }
    else {
      loc = (uint64_t)j & mask;
      while (hs[loc] != ~0ULL) loc = (loc + 1) & mask;
      hs[loc] = (uint64_t)j;
      outv[j - (pop - n)] = j;
    }
  }
  if (shuf) {
    for (int i = n - 1; i >= 1; i--) {
      uint64_t j = rbu(g, (uint64_t)i);
      int t = outv[i]; outv[i] = outv[(int)j]; outv[(int)j] = t;
    }
  }
}
} // namespace nprng

static void build_tab(TriTab* T) {
  nprng::PCG g;
  nprng::seed_pcg0(g);
  int tri[NT][3];
  for (int t = 0; t < NT; t++) nprng::choice_nr(g, 12, 3, tri[t], true);
  int tt[NT];
  nprng::choice_nr(g, 96, NT, tt, true);
  std::sort(tt, tt + NT);
  static const int EC[12][3] = {{0,0,0},{0,1,0},{0,0,1},{0,1,1},
                                {0,0,0},{1,0,0},{0,0,1},{1,0,1},
                                {0,0,0},{1,0,0},{0,1,0},{1,1,0}};
  static const int EA[12] = {0,0,0,0,1,1,1,1,2,2,2,2};
  for (int t = 0; t < NT; t++) {
    int axes = 0;
    for (int k = 0; k < 3; k++) {
      int e = tri[t][k];
      int a = EA[e];
      T->delta[t][k] = a * 117649 + EC[e][0] * 2401 + EC[e][1] * 49 + EC[e][2];
      float b[3] = {(float)EC[e][0], (float)EC[e][1], (float)EC[e][2]};
      b[a] += 0.5f;
      T->bx[t][k] = b[0]; T->by[t][k] = b[1]; T->bz[t][k] = b[2];
      axes |= a << (2 * k);
    }
    T->axes[t] = axes;
    T->tto[t] = tt[t];
  }
}

// ---------------- kernels ----------------
// k_cell: 64 cells/block, 256 threads (4 waves). Wave w computes tris
// [12w, 12w+12) for lane's cell; partials reduced across waves via LDS.
// Topo slab (64*96 floats) is linear in global -> coalesced float4 staging
// into pitch-97 LDS (2 lanes/bank on compute reads = free).
__global__ __launch_bounds__(CB * NW) void k_cell(const float* __restrict__ off,
                                                  const float* __restrict__ topo,
                                                  float4* __restrict__ ws4,
                                                  float* __restrict__ out,
                                                  TriTab tab) {
  __shared__ float lds[CB * PITCH];
  __shared__ float4 red[CB * NW];
  const int tid = threadIdx.x;
  const int lane = tid & 63;     // local cell
  const int wv = tid >> 6;       // tri-quarter
  const int cell0 = blockIdx.x * CB;

  if (blockIdx.x == 0 && tid == 0) *out = 0.0f;  // zero accumulator for k_pair

  // ---- coalesced staging: 64 rows x 24 float4 = 1536 float4, linear ----
  const float4* trow = (const float4*)(topo + (size_t)cell0 * 96);
#pragma unroll
  for (int it = 0; it < (CB * 24) / (CB * NW); ++it) {  // 6 iters
    int ch = tid + CB * NW * it;
    float4 v = trow[ch];
    int r  = ch / 24;
    int c4 = (ch % 24) * 4;
    float* dst = &lds[r * PITCH + c4];
    dst[0] = v.x; dst[1] = v.y; dst[2] = v.z; dst[3] = v.w;
  }
  __syncthreads();

  // ---- per-(cell, quarter) compute ----
  const int cell = cell0 + lane;
  const int z = cell % 48;
  const int y = (cell / 48) % 48;
  const int x = cell / 2304;
  const int base = (x * 49 + y) * 49 + z;
  const float* myrow = &lds[lane * PITCH];
  const int t0 = wv * TPW;

  float s = 0.f, mx = 0.f, my = 0.f, mz = 0.f;
#pragma unroll
  for (int k = 0; k < TPW; k++) {
    int t = t0 + k;
    float p = myrow[tab.tto[t]];
    float d0 = off[base + tab.delta[t][0]];
    float d1 = off[base + tab.delta[t][1]];
    float d2 = off[base + tab.delta[t][2]];
    int axes = tab.axes[t];
    int a0 = axes & 3, a1 = (axes >> 2) & 3, a2 = (axes >> 4) & 3;
    float v0x = tab.bx[t][0] + (a0 == 0 ? d0 : 0.0f);
    float v0y = tab.by[t][0] + (a0 == 1 ? d0 : 0.0f);
    float v0z = tab.bz[t][0] + (a0 == 2 ? d0 : 0.0f);
    float v1x = tab.bx[t][1] + (a1 == 0 ? d1 : 0.0f);
    float v1y = tab.by[t][1] + (a1 == 1 ? d1 : 0.0f);
    float v1z = tab.bz[t][1] + (a1 == 2 ? d1 : 0.0f);
    float v2x = tab.bx[t][2] + (a2 == 0 ? d2 : 0.0f);
    float v2y = tab.by[t][2] + (a2 == 1 ? d2 : 0.0f);
    float v2z = tab.bz[t][2] + (a2 == 2 ? d2 : 0.0f);
    float ux = v1x - v0x, uy = v1y - v0y, uz = v1z - v0z;
    float wx = v2x - v0x, wy = v2y - v0y, wz = v2z - v0z;
    float cxv = uy * wz - uz * wy;
    float cyv = uz * wx - ux * wz;
    float czv = ux * wy - uy * wx;
    float nn = cxv * cxv + cyv * cyv + czv * czv + 1e-8f;
    float rinv = rsqrtf(nn);
    s += p;
    float f = p * rinv;
    mx += f * cxv;
    my += f * cyv;
    mz += f * czv;
  }
  red[tid] = make_float4(s, mx, my, mz);
  __syncthreads();

  // ---- cross-wave combine: wave 0 sums the 4 quarters, writes float4 ----
  if (wv == 0) {
    float4 a = red[lane];
    float4 b = red[lane + 64];
    float4 c = red[lane + 128];
    float4 d = red[lane + 192];
    ws4[cell0 + lane] = make_float4(a.x + b.x + c.x + d.x,
                                    a.y + b.y + c.y + d.y,
                                    a.z + b.z + c.z + d.z,
                                    a.w + b.w + c.w + d.w);
  }
}

__global__ __launch_bounds__(256) void k_pair(const float4* __restrict__ ws4,
                                              float* __restrict__ out) {
  int cell = blockIdx.x * 256 + threadIdx.x;
  int z = cell % 48;
  int y = (cell / 48) % 48;
  int x = cell / 2304;
  float4 a = ws4[cell];
  float acc = a.x * a.x - (a.y * a.y + a.z * a.z + a.w * a.w);
  if (z < 47) {
    float4 b = ws4[cell + 1];
    acc += a.x * b.x - (a.y * b.y + a.z * b.z + a.w * b.w);
  }
  if (y < 47) {
    float4 b = ws4[cell + 48];
    acc += a.x * b.x - (a.y * b.y + a.z * b.z + a.w * b.w);
  }
  if (x < 47) {
    float4 b = ws4[cell + 2304];
    acc += a.x * b.x - (a.y * b.y + a.z * b.z + a.w * b.w);
  }
  acc *= 2.0f;
  for (int o = 32; o > 0; o >>= 1) acc += __shfl_down(acc, o, 64);
  __shared__ float lds[4];
  int lane = threadIdx.x & 63;
  int w = threadIdx.x >> 6;
  if (lane == 0) lds[w] = acc;
  __syncthreads();
  if (threadIdx.x == 0) atomicAdd(out, lds[0] + lds[1] + lds[2] + lds[3]);
}

extern "C" void kernel_launch(void* const* d_in, const int* in_sizes, int n_in,
                              void* d_out, int out_size, void* d_ws, size_t ws_size,
                              hipStream_t stream) {
  const float* off  = (const float*)d_in[0];   // [3,49,49,49] f32
  const float* topo = (const float*)d_in[1];   // [110592,96] f32
  float4* ws4 = (float4*)d_ws;                 // 110592 float4 = 1.77 MB
  float* out  = (float*)d_out;                 // scalar f32

  TriTab T;
  build_tab(&T);

  k_cell<<<dim3(NCELLS / CB), dim3(CB * NW), 0, stream>>>(off, topo, ws4, out, T);
  k_pair<<<dim3(NCELLS / 256), dim3(256), 0, stream>>>(ws4, out);
}